// Round 8
// baseline (4811.946 us; speedup 1.0000x reference)
//
#include <hip/hip_runtime.h>

#define TLEN 512
#define HDIM 512
#define NGRP 8
#define MROW 32
#define NL0  8
#define WPG  24
#define GRID (NGRP*WPG)
#define U0   64
#define U1   32
#define HSZB 32768          // bytes per parity buffer per group (32 rows x 1024B)
#define NPAR 4

typedef __attribute__((ext_vector_type(8))) short bf16x8;
typedef __attribute__((ext_vector_type(4))) float f32x4;
typedef __attribute__((ext_vector_type(4))) unsigned u32x4;

#define AT_LD64(p)   __hip_atomic_load((const unsigned long long*)(p), __ATOMIC_RELAXED, __HIP_MEMORY_SCOPE_AGENT)
#define AT_LD32I(p)  __hip_atomic_load((const int*)(p), __ATOMIC_RELAXED, __HIP_MEMORY_SCOPE_AGENT)
#define AT_ST32I(p,v) __hip_atomic_store((int*)(p), (v), __ATOMIC_RELAXED, __HIP_MEMORY_SCOPE_AGENT)
#define AT_ST16(p,v) __hip_atomic_store((unsigned short*)(p), (v), __ATOMIC_RELAXED, __HIP_MEMORY_SCOPE_AGENT)
#define AT_ST32F(p,v) __hip_atomic_store((float*)(p), (v), __ATOMIC_RELAXED, __HIP_MEMORY_SCOPE_AGENT)

// 32 x 16B MALL-coherent loads (sc0 sc1) + s_waitcnt vmcnt(0) IN THE SAME asm
// block — outputs are architecturally valid when the block retires. (R7 bug:
// detached waitcnt let the compiler schedule MFMA before the wait.)
// qa[i]: m-tile0/1 frags ks=0..7 ; qb[i]: frags ks=8..15.
#define LDF32_WAIT(qa, qb, base)                                              \
  asm volatile(                                                               \
    "global_load_dwordx4 %[q0], %[a], off offset:0    sc0 sc1\n\t"            \
    "global_load_dwordx4 %[q1], %[a], off offset:64   sc0 sc1\n\t"            \
    "global_load_dwordx4 %[q2], %[a], off offset:128  sc0 sc1\n\t"            \
    "global_load_dwordx4 %[q3], %[a], off offset:192  sc0 sc1\n\t"            \
    "global_load_dwordx4 %[q4], %[a], off offset:256  sc0 sc1\n\t"            \
    "global_load_dwordx4 %[q5], %[a], off offset:320  sc0 sc1\n\t"            \
    "global_load_dwordx4 %[q6], %[a], off offset:384  sc0 sc1\n\t"            \
    "global_load_dwordx4 %[q7], %[a], off offset:448  sc0 sc1\n\t"            \
    "global_load_dwordx4 %[q8], %[b], off offset:0    sc0 sc1\n\t"            \
    "global_load_dwordx4 %[q9], %[b], off offset:64   sc0 sc1\n\t"            \
    "global_load_dwordx4 %[qA], %[b], off offset:128  sc0 sc1\n\t"            \
    "global_load_dwordx4 %[qB], %[b], off offset:192  sc0 sc1\n\t"            \
    "global_load_dwordx4 %[qC], %[b], off offset:256  sc0 sc1\n\t"            \
    "global_load_dwordx4 %[qD], %[b], off offset:320  sc0 sc1\n\t"            \
    "global_load_dwordx4 %[qE], %[b], off offset:384  sc0 sc1\n\t"            \
    "global_load_dwordx4 %[qF], %[b], off offset:448  sc0 sc1\n\t"            \
    "global_load_dwordx4 %[r0], %[a], off offset:512  sc0 sc1\n\t"            \
    "global_load_dwordx4 %[r1], %[a], off offset:576  sc0 sc1\n\t"            \
    "global_load_dwordx4 %[r2], %[a], off offset:640  sc0 sc1\n\t"            \
    "global_load_dwordx4 %[r3], %[a], off offset:704  sc0 sc1\n\t"            \
    "global_load_dwordx4 %[r4], %[a], off offset:768  sc0 sc1\n\t"            \
    "global_load_dwordx4 %[r5], %[a], off offset:832  sc0 sc1\n\t"            \
    "global_load_dwordx4 %[r6], %[a], off offset:896  sc0 sc1\n\t"            \
    "global_load_dwordx4 %[r7], %[a], off offset:960  sc0 sc1\n\t"            \
    "global_load_dwordx4 %[r8], %[b], off offset:512  sc0 sc1\n\t"            \
    "global_load_dwordx4 %[r9], %[b], off offset:576  sc0 sc1\n\t"            \
    "global_load_dwordx4 %[rA], %[b], off offset:640  sc0 sc1\n\t"            \
    "global_load_dwordx4 %[rB], %[b], off offset:704  sc0 sc1\n\t"            \
    "global_load_dwordx4 %[rC], %[b], off offset:768  sc0 sc1\n\t"            \
    "global_load_dwordx4 %[rD], %[b], off offset:832  sc0 sc1\n\t"            \
    "global_load_dwordx4 %[rE], %[b], off offset:896  sc0 sc1\n\t"            \
    "global_load_dwordx4 %[rF], %[b], off offset:960  sc0 sc1\n\t"            \
    "s_waitcnt vmcnt(0)"                                                      \
    : [q0]"=&v"(qa[0]),[q1]"=&v"(qa[1]),[q2]"=&v"(qa[2]),[q3]"=&v"(qa[3]),    \
      [q4]"=&v"(qa[4]),[q5]"=&v"(qa[5]),[q6]"=&v"(qa[6]),[q7]"=&v"(qa[7]),    \
      [q8]"=&v"(qa[8]),[q9]"=&v"(qa[9]),[qA]"=&v"(qa[10]),[qB]"=&v"(qa[11]),  \
      [qC]"=&v"(qa[12]),[qD]"=&v"(qa[13]),[qE]"=&v"(qa[14]),[qF]"=&v"(qa[15]),\
      [r0]"=&v"(qb[0]),[r1]"=&v"(qb[1]),[r2]"=&v"(qb[2]),[r3]"=&v"(qb[3]),    \
      [r4]"=&v"(qb[4]),[r5]"=&v"(qb[5]),[r6]"=&v"(qb[6]),[r7]"=&v"(qb[7]),    \
      [r8]"=&v"(qb[8]),[r9]"=&v"(qb[9]),[rA]"=&v"(qb[10]),[rB]"=&v"(qb[11]),  \
      [rC]"=&v"(qb[12]),[rD]"=&v"(qb[13]),[rE]"=&v"(qb[14]),[rF]"=&v"(qb[15]) \
    : [a]"v"(base), [b]"v"(base + 16*1024ull)                                 \
    : "memory")

__device__ __forceinline__ unsigned short f2bf(float f){
  unsigned u = __builtin_bit_cast(unsigned, f);
  u = (u + 0x7FFFu + ((u>>16)&1u)) >> 16;   // RNE
  return (unsigned short)u;
}
__device__ __forceinline__ float sigm(float v){ return 1.f/(1.f + __expf(-v)); }
__device__ __forceinline__ float tanh_f(float v){ return 1.f - 2.f/(__expf(2.f*v)+1.f); }

// Poll the 24 per-WG step flags (agent scope): lanes 0-7 -> F0 (L0 WGs),
// lanes 8-23 -> F1 (L1 WGs). All waves poll redundantly (no syncthreads).
__device__ __forceinline__ void pollf(const int* gf, int needA, int needB, int lane){
  int slot = (lane<24)? lane : 24;
  int need = (lane<8)? needA : ((lane<24)? needB : -1000000);
  const int* p = gf + slot*16;      // 64B-spaced
  unsigned wd=0; int v;
  do { v = AT_LD32I(p); } while (__ballot(v < need) && ++wd < (1u<<19));
}

extern "C" __global__ void __launch_bounds__(256,1)
gru_persistent(const float* __restrict__ x,
               const float* __restrict__ Wi0,
               const float* __restrict__ bi0,
               const float* __restrict__ Wi1,
               const float* __restrict__ bi1,
               const float* __restrict__ Wh,
               const float* __restrict__ bh,
               const float* __restrict__ fcw,
               const float* __restrict__ fcb,
               float* __restrict__ out,
               int* __restrict__ bar,
               char* __restrict__ h0g,
               char* __restrict__ h1g,
               float* __restrict__ h1f)
{
  __shared__ float shG[MROW*192];                 // 24576 B — only LDS use

  const int tid  = threadIdx.x;
  const int lane = tid & 63;
  const int w    = tid >> 6;
  const int bid  = blockIdx.x;
  const int grp  = bid & 7;
  const int wgid = bid >> 3;            // 0..7 = L0, 8..23 = L1
  const bool isL0 = (wgid < NL0);
  const int g32 = grp*32;

  int*  gf  = bar + grp*512;            // 24 flags, 64B-spaced (memset 0)
  char* h0c = h0g + (size_t)grp*NPAR*HSZB;
  char* h1c = h1g + (size_t)grp*NPAR*HSZB;

  if (isL0){
    // ---------------- layer-0 workgroup: units [u0, u0+64) ----------------
    const int u0   = wgid*U0;
    const int colb = w*48;

    bf16x8 bfr[3][16];                   // pinned Wh[0] fragments
    #pragma unroll
    for (int nt=0; nt<3; ++nt){
      int col = colb + nt*16 + (lane&15);
      int g = col>>6, uu = col&63;
      const float* wrow = Wh + (size_t)(g*HDIM + u0 + uu)*HDIM;   // Wh[0][g][u][:]
      #pragma unroll
      for (int ks=0; ks<16; ++ks){
        int k = ks*32 + (lane>>4)*8;
        const float4 f0 = *(const float4*)(wrow + k);
        const float4 f1 = *(const float4*)(wrow + k + 4);
        bf16x8 v;
        v[0]=(short)f2bf(f0.x); v[1]=(short)f2bf(f0.y); v[2]=(short)f2bf(f0.z); v[3]=(short)f2bf(f0.w);
        v[4]=(short)f2bf(f1.x); v[5]=(short)f2bf(f1.y); v[6]=(short)f2bf(f1.z); v[7]=(short)f2bf(f1.w);
        bfr[nt][ks]=v;
      }
    }
    const int ua   = tid & 63;
    const int brow = (tid>>6)*8;
    float wi0v[3], bi0v[3], bh0v[3];
    #pragma unroll
    for (int g=0; g<3; ++g){
      wi0v[g] = Wi0[g*HDIM + u0+ua];
      bi0v[g] = bi0[g*HDIM + u0+ua];
      bh0v[g] = bh [g*HDIM + u0+ua];
    }
    float h_own[8];
    #pragma unroll
    for (int j=0;j<8;++j) h_own[j]=0.f;

    for (int t=1; t<=TLEN; ++t){
      // RAW: h0[t-1] ready (F0>=t-1). WAR: overwriting h0[t-4] needs L1 past
      // step t-4 (F1>=t-4); L0 peers past t-3 is implied by F0>=t-1.
      pollf(gf, t-1, t-4, lane);
      unsigned long long a0 = (unsigned long long)(h0c + ((t-1)&3)*HSZB)
                              + (unsigned)((lane&15)*1024 + (lane>>4)*16);
      u32x4 qa[16], qb[16];
      LDF32_WAIT(qa, qb, a0);
      f32x4 acc[2][3] = {};
      #pragma unroll
      for (int ks=0; ks<16; ++ks){
        bf16x8 av0 = __builtin_bit_cast(bf16x8, (ks<8)? qa[ks]   : qb[ks-8]);
        bf16x8 av1 = __builtin_bit_cast(bf16x8, (ks<8)? qa[ks+8] : qb[ks]);
        #pragma unroll
        for (int nt=0; nt<3; ++nt){
          acc[0][nt] = __builtin_amdgcn_mfma_f32_16x16x32_bf16(av0, bfr[nt][ks], acc[0][nt],0,0,0);
          acc[1][nt] = __builtin_amdgcn_mfma_f32_16x16x32_bf16(av1, bfr[nt][ks], acc[1][nt],0,0,0);
        }
      }
      #pragma unroll
      for (int mt=0; mt<2; ++mt)
        #pragma unroll
        for (int nt=0; nt<3; ++nt)
          #pragma unroll
          for (int j=0;j<4;++j){
            int b = mt*16 + (lane>>4)*4 + j;
            shG[b*192 + colb + nt*16 + (lane&15)] = acc[mt][nt][j];
          }
      __syncthreads();
      unsigned short* dstA = (unsigned short*)(h0c + (t&3)*HSZB);
      #pragma unroll
      for (int j=0;j<8;++j){
        int b = brow + j;
        float xv = x[(g32+b)*TLEN + (t-1)];
        float G0 = shG[b*192 + ua]       + bh0v[0];
        float G1 = shG[b*192 + 64 + ua]  + bh0v[1];
        float G2 = shG[b*192 + 128 + ua] + bh0v[2];
        float r_ = sigm(fmaf(xv, wi0v[0], bi0v[0]) + G0);
        float z_ = sigm(fmaf(xv, wi0v[1], bi0v[1]) + G1);
        float n_ = tanh_f(fmaf(xv, wi0v[2], bi0v[2]) + r_*G2);
        float hn = (1.f - z_)*n_ + z_*h_own[j];
        h_own[j] = hn;
        AT_ST16(&dstA[b*HDIM + u0 + ua], f2bf(hn));
      }
      asm volatile("s_waitcnt vmcnt(0)" ::: "memory");  // my h stores visible
      __syncthreads();                                  // whole WG drained
      if (tid==0) AT_ST32I(gf + wgid*16, t);
    }
    // final FC by WG0 of the group: wait for all F1 >= 512, then 32x2 GEMV
    if (wgid==0){
      { unsigned wd=0; int v;
        const int* p = gf + (8 + (lane&15))*16;
        do { v = AT_LD32I(p); } while (__ballot(v < TLEN) && ++wd < (1u<<19));
      }
      __syncthreads();
      int p = tid>>2, kl = tid&3;
      int b = p>>1, o = p&1;
      const char* h8 = (const char*)(h1f + (size_t)(g32+b)*HDIM + kl*128);
      const float2* w2 = (const float2*)(fcw + o*HDIM + kl*128);
      float a2 = 0.f;
      #pragma unroll
      for (int k=0;k<64;++k){
        unsigned long long v = AT_LD64(h8 + k*8);
        float2 hv = __builtin_bit_cast(float2, v);
        float2 wv = w2[k];
        a2 = fmaf(hv.x, wv.x, fmaf(hv.y, wv.y, a2));
      }
      a2 += __shfl_xor(a2, 1);
      a2 += __shfl_xor(a2, 2);
      if (kl==0) out[(g32+b)*2 + o] = a2 + fcb[o];
    }
  } else {
    // ---------------- layer-1 workgroup: units [u1, u1+32) ----------------
    const int u1   = (wgid-NL0)*U1;
    const int colb = (w<2) ? w*48 : 96 + (w-2)*48;  // 0..95 gi (vs h0), 96..191 gh (vs h1)

    bf16x8 bfr[3][16];
    #pragma unroll
    for (int nt=0; nt<3; ++nt){
      int col = colb + nt*16 + (lane&15);
      const float* wrow;
      if (w < 2){ int g = col>>5, uu = col&31;
        wrow = Wi1 + (size_t)(g*HDIM + u1 + uu)*HDIM;             // Wi_rest[0][g][u][:]
      } else {    int c2 = col-96; int g = c2>>5, uu = c2&31;
        wrow = Wh + (size_t)((3+g)*HDIM + u1 + uu)*HDIM;          // Wh[1][g][u][:]
      }
      #pragma unroll
      for (int ks=0; ks<16; ++ks){
        int k = ks*32 + (lane>>4)*8;
        const float4 f0 = *(const float4*)(wrow + k);
        const float4 f1 = *(const float4*)(wrow + k + 4);
        bf16x8 v;
        v[0]=(short)f2bf(f0.x); v[1]=(short)f2bf(f0.y); v[2]=(short)f2bf(f0.z); v[3]=(short)f2bf(f0.w);
        v[4]=(short)f2bf(f1.x); v[5]=(short)f2bf(f1.y); v[6]=(short)f2bf(f1.z); v[7]=(short)f2bf(f1.w);
        bfr[nt][ks]=v;
      }
    }
    const int ua   = tid & 31;
    const int brow = (tid>>5)*4;
    float bi1v[3], bh1v[3];
    #pragma unroll
    for (int g=0; g<3; ++g){
      bi1v[g] = bi1[g*HDIM + u1+ua];
      bh1v[g] = bh [(3+g)*HDIM + u1+ua];
    }
    float h_own[4];
    #pragma unroll
    for (int j=0;j<4;++j) h_own[j]=0.f;

    for (int t=1; t<=TLEN; ++t){
      // RAW: h0[t] ready (F0>=t), h1[t-1] ready (F1>=t-1).
      // WAR: overwriting h1[t-4] needs F1>=t-3, implied by F1>=t-1.
      pollf(gf, t, t-1, lane);
      const char* abase = (w<2) ? (h0c + (t&3)*HSZB)       // gi input: h0[t]
                                : (h1c + ((t-1)&3)*HSZB);  // gh input: h1[t-1]
      unsigned long long a0 = (unsigned long long)abase
                              + (unsigned)((lane&15)*1024 + (lane>>4)*16);
      u32x4 qa[16], qb[16];
      LDF32_WAIT(qa, qb, a0);
      f32x4 acc[2][3] = {};
      #pragma unroll
      for (int ks=0; ks<16; ++ks){
        bf16x8 av0 = __builtin_bit_cast(bf16x8, (ks<8)? qa[ks]   : qb[ks-8]);
        bf16x8 av1 = __builtin_bit_cast(bf16x8, (ks<8)? qa[ks+8] : qb[ks]);
        #pragma unroll
        for (int nt=0; nt<3; ++nt){
          acc[0][nt] = __builtin_amdgcn_mfma_f32_16x16x32_bf16(av0, bfr[nt][ks], acc[0][nt],0,0,0);
          acc[1][nt] = __builtin_amdgcn_mfma_f32_16x16x32_bf16(av1, bfr[nt][ks], acc[1][nt],0,0,0);
        }
      }
      #pragma unroll
      for (int mt=0; mt<2; ++mt)
        #pragma unroll
        for (int nt=0; nt<3; ++nt)
          #pragma unroll
          for (int j=0;j<4;++j){
            int b = mt*16 + (lane>>4)*4 + j;
            shG[b*192 + colb + nt*16 + (lane&15)] = acc[mt][nt][j];
          }
      __syncthreads();
      unsigned short* dstB = (unsigned short*)(h1c + (t&3)*HSZB);
      #pragma unroll
      for (int j=0;j<4;++j){
        int b = brow + j;
        float gi0 = shG[b*192 + ua]        + bi1v[0];
        float gi1 = shG[b*192 + 32 + ua]   + bi1v[1];
        float gi2 = shG[b*192 + 64 + ua]   + bi1v[2];
        float gh0 = shG[b*192 + 96 + ua]   + bh1v[0];
        float gh1 = shG[b*192 + 128 + ua]  + bh1v[1];
        float gh2 = shG[b*192 + 160 + ua]  + bh1v[2];
        float r_ = sigm(gi0+gh0);
        float z_ = sigm(gi1+gh1);
        float n_ = tanh_f(gi2 + r_*gh2);
        float hn = (1.f - z_)*n_ + z_*h_own[j];
        h_own[j] = hn;
        AT_ST16(&dstB[b*HDIM + u1 + ua], f2bf(hn));
        if (t == TLEN) AT_ST32F(&h1f[(size_t)(g32+b)*HDIM + u1 + ua], hn);
      }
      asm volatile("s_waitcnt vmcnt(0)" ::: "memory");
      __syncthreads();
      if (tid==0) AT_ST32I(gf + wgid*16, t);
    }
  }
}

extern "C" void kernel_launch(void* const* d_in, const int* in_sizes, int n_in,
                              void* d_out, int out_size, void* d_ws, size_t ws_size,
                              hipStream_t stream)
{
  const float* x   = (const float*)d_in[0];
  const float* Wi0 = (const float*)d_in[1];
  const float* bi0 = (const float*)d_in[2];
  const float* Wi1 = (const float*)d_in[3];
  const float* bi1 = (const float*)d_in[4];
  const float* Wh  = (const float*)d_in[5];
  const float* bh  = (const float*)d_in[6];
  const float* fcw = (const float*)d_in[7];
  const float* fcb = (const float*)d_in[8];
  float* out = (float*)d_out;

  // ws layout: [0,16K) flags | h0: 8 grp x 4 par x 32KB | h1 same | h1f fp32
  int*   bar = (int*)d_ws;
  char*  h0g = (char*)d_ws + 16384;
  char*  h1g = h0g + (size_t)NGRP*NPAR*HSZB;        // +1 MB
  float* h1f = (float*)(h1g + (size_t)NGRP*NPAR*HSZB);

  size_t clr = 16384 + 2*(size_t)NGRP*NPAR*HSZB + (size_t)256*HDIM*4;
  hipMemsetAsync(d_ws, 0, clr, stream);
  gru_persistent<<<GRID, 256, 0, stream>>>(x,Wi0,bi0,Wi1,bi1,Wh,bh,fcw,fcb,out,
                                           bar,h0g,h1g,h1f);
}